// Round 2
// baseline (13999.030 us; speedup 1.0000x reference)
//
#include <hip/hip_runtime.h>
#include <hip/hip_bf16.h>

// TSGCN: GCN(2 layers, fused) -> GRU(4096->256) -> GRU(256->256) -> FC head
// B=32 S=512 N=64 F=16 G=64 H=256. All fp32.
// R1: single-block-per-batch GRU (weights in VGPRs, zero cross-block sync).

#define EPS_BN 1e-5f

typedef float f32x4 __attribute__((ext_vector_type(4)));

// ------------------------------------------------- pack Whh for GRU kernel
// GRU thread t (0..767) owns full gate-row t: w[i] = Whh[t][i], i in 0..255.
// Stored so a per-thread float4 load of elems 4q..4q+3 is coalesced across t:
//   wp[(q*768 + t)*4 + e] = Whh[t*256 + 4q + e]
__global__ void k_pack_whh(const float* __restrict__ whh, float* __restrict__ wp) {
  int idx = blockIdx.x * 256 + threadIdx.x;   // idx = t*256 + i
  if (idx >= 768 * 256) return;
  int t = idx >> 8;
  int i = idx & 255;
  wp[((i >> 2) * 768 + t) * 4 + (i & 3)] = whh[idx];
}

// ------------------------------------------------------------- fused GCN
// One block per (b,s). seq row (local) = relu(A@((bn(relu(A@(X@W0)+b0)))@W1)+b1)
__global__ __launch_bounds__(256) void k_gcn(
    const float* __restrict__ x, const float* __restrict__ adj,
    const float* __restrict__ W0, const float* __restrict__ b0,
    const float* __restrict__ W1, const float* __restrict__ b1,
    const float* __restrict__ bn_g, const float* __restrict__ bn_b,
    const float* __restrict__ bn_m, const float* __restrict__ bn_v,
    float* __restrict__ seq, int base)
{
  __shared__ float As[4096];   // adj [64][64]
  __shared__ float Xs[1024];   // x   [64][16]
  __shared__ float Hs[4096];   // h1  [64][64]
  __shared__ float Qs[4096];   // h1@W1 [64][64]
  __shared__ float bnm_s[64], bns_s[64], bnb_s[64];

  const int t = threadIdx.x;
  const int lane = t & 63;     // g column
  const int w = t >> 6;        // wave 0..3
  const int m = base + blockIdx.x;

  { // stage adj + x
    const float4* a4 = (const float4*)adj;
    float4* s4 = (float4*)As;
#pragma unroll
    for (int p = 0; p < 4; ++p) s4[t + 256 * p] = a4[t + 256 * p];
    ((float4*)Xs)[t] = ((const float4*)(x + (size_t)m * 1024))[t];
  }
  if (t < 64) {
    bns_s[t] = rsqrtf(bn_v[t] + EPS_BN) * bn_g[t];
    bnm_s[t] = bn_m[t];
    bnb_s[t] = bn_b[t];
  }
  float w0r[16];
#pragma unroll
  for (int f = 0; f < 16; ++f) w0r[f] = W0[f * 64 + lane];
  const float b0v = b0[lane], b1v = b1[lane];
  __syncthreads();

  // P[v] = (X@W0)[v][lane]  (per-thread column, redundant across waves)
  float p[64];
#pragma unroll
  for (int v = 0; v < 64; ++v) {
    float acc = 0.f;
#pragma unroll
    for (int f = 0; f < 16; ++f) acc += Xs[v * 16 + f] * w0r[f];
    p[v] = acc;
  }
  // H1[u][lane] for u in this wave's 16 rows
#pragma unroll
  for (int uu = 0; uu < 16; ++uu) {
    int u = w * 16 + uu;
    float acc = 0.f;
#pragma unroll
    for (int v = 0; v < 64; ++v) acc += As[u * 64 + v] * p[v];
    float h1 = fmaxf(acc + b0v, 0.f);
    h1 = (h1 - bnm_s[u]) * bns_s[u] + bnb_s[u];
    Hs[u * 64 + lane] = h1;
  }
  __syncthreads();
  float w1r[64];
#pragma unroll
  for (int f = 0; f < 64; ++f) w1r[f] = W1[f * 64 + lane];
  // Q[v][lane] = (H1@W1)[v][lane], v split across waves
#pragma unroll
  for (int vv = 0; vv < 16; ++vv) {
    int v = w * 16 + vv;
    float acc = 0.f;
#pragma unroll
    for (int f = 0; f < 64; ++f) acc += Hs[v * 64 + f] * w1r[f];
    Qs[v * 64 + lane] = acc;
  }
  __syncthreads();
  float q[64];
#pragma unroll
  for (int v = 0; v < 64; ++v) q[v] = Qs[v * 64 + lane];
  float* outrow = seq + (size_t)blockIdx.x * 4096;
#pragma unroll
  for (int uu = 0; uu < 16; ++uu) {
    int u = w * 16 + uu;
    float acc = 0.f;
#pragma unroll
    for (int v = 0; v < 64; ++v) acc += As[u * 64 + v] * q[v];
    outrow[u * 64 + lane] = fmaxf(acc + b1v, 0.f);
  }
}

// --------------------------------------------------------- GEMM  C = A@B^T + bias
// A: [M][K] row-major (local rows), B: [768][K] row-major, C: [rows][768] (pre-offset)
#define BM 128
#define BN 128
#define BKK 16
__global__ __launch_bounds__(256) void k_gemm_nt(
    const float* __restrict__ A, int lda,
    const float* __restrict__ Bm,
    const float* __restrict__ bias,
    float* __restrict__ C,
    int K, int mBlocks)
{
  __shared__ float As[BKK][BM + 4];
  __shared__ float Bs[BKK][BN + 4];
  const int bid = blockIdx.x;
  const int mb = bid % mBlocks;
  const int nb = bid / mBlocks;
  const int m0 = mb * BM, n0 = nb * BN;
  const int t = threadIdx.x;
  const int tx = t & 15, ty = t >> 4;
  const int lr = t >> 2;           // 0..63
  const int lk = (t & 3) * 4;      // 0,4,8,12

  const float* Ap  = A  + (size_t)(m0 + lr) * lda + lk;
  const float* Ap2 = Ap + (size_t)64 * lda;
  const float* Bp  = Bm + (size_t)(n0 + lr) * K + lk;
  const float* Bp2 = Bp + (size_t)64 * K;

  float acc[8][8] = {};
  for (int kt = 0; kt < K; kt += BKK) {
    const float4 a0 = *(const float4*)(Ap + kt);
    const float4 a1 = *(const float4*)(Ap2 + kt);
    const float4 g0 = *(const float4*)(Bp + kt);
    const float4 g1 = *(const float4*)(Bp2 + kt);
    __syncthreads();
    As[lk + 0][lr] = a0.x; As[lk + 1][lr] = a0.y; As[lk + 2][lr] = a0.z; As[lk + 3][lr] = a0.w;
    As[lk + 0][64 + lr] = a1.x; As[lk + 1][64 + lr] = a1.y; As[lk + 2][64 + lr] = a1.z; As[lk + 3][64 + lr] = a1.w;
    Bs[lk + 0][lr] = g0.x; Bs[lk + 1][lr] = g0.y; Bs[lk + 2][lr] = g0.z; Bs[lk + 3][lr] = g0.w;
    Bs[lk + 0][64 + lr] = g1.x; Bs[lk + 1][64 + lr] = g1.y; Bs[lk + 2][64 + lr] = g1.z; Bs[lk + 3][64 + lr] = g1.w;
    __syncthreads();
#pragma unroll
    for (int k = 0; k < BKK; ++k) {
      const float4 av0 = *(const float4*)&As[k][ty * 8];
      const float4 av1 = *(const float4*)&As[k][ty * 8 + 4];
      const float4 bv0 = *(const float4*)&Bs[k][tx * 8];
      const float4 bv1 = *(const float4*)&Bs[k][tx * 8 + 4];
      const float a_[8] = {av0.x, av0.y, av0.z, av0.w, av1.x, av1.y, av1.z, av1.w};
      const float b_[8] = {bv0.x, bv0.y, bv0.z, bv0.w, bv1.x, bv1.y, bv1.z, bv1.w};
#pragma unroll
      for (int im = 0; im < 8; ++im)
#pragma unroll
        for (int jn = 0; jn < 8; ++jn)
          acc[im][jn] += a_[im] * b_[jn];
    }
  }
#pragma unroll
  for (int im = 0; im < 8; ++im) {
    const int mrow = m0 + ty * 8 + im;
    float* crow = C + (size_t)mrow * 768 + n0 + tx * 8;
#pragma unroll
    for (int jn = 0; jn < 8; ++jn)
      crow[jn] = acc[im][jn] + bias[n0 + tx * 8 + jn];
  }
}

// ------------------------------------------------------------------ GRU layer
// ONE block per batch. 768 threads; thread t owns gate-row t of Whh in VGPRs
// (64 x f32x4 = 256 floats). Per step: reg-dot vs h (LDS, broadcast) -> gh[t]
// -> barrier -> t<256 does gate math + h update -> barrier. No global sync.
__global__ __launch_bounds__(768, 3) void k_gru(
    const float* __restrict__ gi,   // [32*512][768]
    const float* __restrict__ wp,   // packed Whh (see k_pack_whh)
    const float* __restrict__ bhh,  // [768]
    float* __restrict__ ys)         // [32*512][256]
{
  const int b = blockIdx.x;
  const int t = threadIdx.x;

  __shared__ float h_s[256];
  __shared__ float gh[768];

  // weights: row t, 64 float4 chunks, coalesced across threads
  f32x4 w[64];
#pragma unroll
  for (int q = 0; q < 64; ++q)
    w[q] = *(const f32x4*)&wp[(size_t)(q * 768 + t) * 4];

  float br = 0.f, bz = 0.f, bn = 0.f;
  if (t < 256) {
    br = bhh[t]; bz = bhh[256 + t]; bn = bhh[512 + t];
    h_s[t] = 0.f;
  }
  __syncthreads();

  const float* gib = gi + (size_t)b * 512 * 768;
  for (int step = 0; step < 512; ++step) {
    // issue gi loads early; latency hides under the dot
    float ir = 0.f, iz = 0.f, inn = 0.f;
    if (t < 256) {
      const float* g = gib + (size_t)step * 768;
      ir = g[t]; iz = g[256 + t]; inn = g[512 + t];
    }
    // dot: w . h  (h broadcast from LDS, two chains for ILP)
    const f32x4* h4 = (const f32x4*)h_s;
    f32x4 a0 = {0.f, 0.f, 0.f, 0.f}, a1 = {0.f, 0.f, 0.f, 0.f};
#pragma unroll
    for (int q = 0; q < 64; q += 2) {
      a0 += w[q] * h4[q];
      a1 += w[q + 1] * h4[q + 1];
    }
    const f32x4 a = a0 + a1;
    gh[t] = a.x + a.y + a.z + a.w;
    __syncthreads();

    if (t < 256) {
      const float hr = gh[t] + br;
      const float hz = gh[256 + t] + bz;
      const float hn = gh[512 + t] + bn;
      const float r = 1.f / (1.f + expf(-(ir + hr)));
      const float z = 1.f / (1.f + expf(-(iz + hz)));
      const float n = tanhf(inn + r * hn);
      const float hnew = (1.f - z) * n + z * h_s[t];
      h_s[t] = hnew;
      ys[((size_t)b * 512 + step) * 256 + t] = hnew;
    }
    __syncthreads();
  }
}

// ------------------------------------------------------------------ FC head
__global__ __launch_bounds__(128) void k_head(
    const float* __restrict__ ys1,
    const float* __restrict__ fc1w, const float* __restrict__ fc1b,
    const float* __restrict__ fc2w, const float* __restrict__ fc2b,
    float* __restrict__ out)
{
  __shared__ float last[256];
  __shared__ float o1[128];
  const int b = blockIdx.x, t = threadIdx.x;
  const float* src = ys1 + (size_t)(b * 512 + 511) * 256;
  last[t] = src[t];
  last[128 + t] = src[128 + t];
  __syncthreads();
  float acc = fc1b[t];
#pragma unroll 8
  for (int k = 0; k < 256; ++k) acc += last[k] * fc1w[k * 128 + t];
  o1[t] = fmaxf(acc, 0.f);
  __syncthreads();
  if (t < 64) {
    float acc2 = fc2b[t];
#pragma unroll 8
    for (int i = 0; i < 128; ++i) acc2 += o1[i] * fc2w[i * 64 + t];
    out[b * 64 + t] = acc2;
  }
}

// ------------------------------------------------------------------ launcher
extern "C" void kernel_launch(void* const* d_in, const int* in_sizes, int n_in,
                              void* d_out, int out_size, void* d_ws, size_t ws_size,
                              hipStream_t stream)
{
  const float* x    = (const float*)d_in[0];
  const float* adj  = (const float*)d_in[1];
  const float* W0   = (const float*)d_in[2];
  const float* b0   = (const float*)d_in[3];
  const float* W1   = (const float*)d_in[4];
  const float* b1   = (const float*)d_in[5];
  const float* bng  = (const float*)d_in[6];
  const float* bnbb = (const float*)d_in[7];
  const float* bnm  = (const float*)d_in[8];
  const float* bnv  = (const float*)d_in[9];
  const float* Wih0 = (const float*)d_in[10];
  const float* Whh0 = (const float*)d_in[11];
  const float* bih0 = (const float*)d_in[12];
  const float* bhh0 = (const float*)d_in[13];
  const float* Wih1 = (const float*)d_in[14];
  const float* Whh1 = (const float*)d_in[15];
  const float* bih1 = (const float*)d_in[16];
  const float* bhh1 = (const float*)d_in[17];
  const float* fc1w = (const float*)d_in[18];
  const float* fc1b = (const float*)d_in[19];
  const float* fc2w = (const float*)d_in[20];
  const float* fc2b = (const float*)d_in[21];
  float* out = (float*)d_out;

  // workspace layout (floats): seqbuf(CHUNK*4096) | gi(16384*768) | ys0(16384*256)
  //                            | wp0(196608) | wp1(196608)
  float* ws = (float*)d_ws;
  const size_t fixed = (size_t)16384 * 768 + (size_t)16384 * 256 + 2 * 196608;
  int CHUNK = 16384;
  while (CHUNK > 128 && ((size_t)CHUNK * 4096 + fixed) * 4 > ws_size) CHUNK >>= 1;

  size_t off = 0;
  float* seqbuf = ws + off; off += (size_t)CHUNK * 4096;
  float* gi     = ws + off; off += (size_t)16384 * 768;
  float* ys0    = ws + off; off += (size_t)16384 * 256;
  float* wp0    = ws + off; off += 196608;
  float* wp1    = ws + off; off += 196608;
  float* ys1    = ys0;                // ys0 dead after gi1 GEMM -> reuse

  k_pack_whh<<<(196608 + 255) / 256, 256, 0, stream>>>(Whh0, wp0);
  k_pack_whh<<<(196608 + 255) / 256, 256, 0, stream>>>(Whh1, wp1);

  const int nChunks = 16384 / CHUNK;
  for (int ci = 0; ci < nChunks; ++ci) {
    const int base = ci * CHUNK;
    k_gcn<<<CHUNK, 256, 0, stream>>>(x, adj, W0, b0, W1, b1, bng, bnbb, bnm, bnv, seqbuf, base);
    const int mB = CHUNK / BM;
    k_gemm_nt<<<mB * 6, 256, 0, stream>>>(seqbuf, 4096, Wih0, bih0, gi + (size_t)base * 768, 4096, mB);
  }
  k_gru<<<32, 768, 0, stream>>>(gi, wp0, bhh0, ys0);
  k_gemm_nt<<<128 * 6, 256, 0, stream>>>(ys0, 256, Wih1, bih1, gi, 256, 128);
  k_gru<<<32, 768, 0, stream>>>(gi, wp1, bhh1, ys1);
  k_head<<<32, 128, 0, stream>>>(ys1, fc1w, fc1b, fc2w, fc2b, out);
}

// Round 3
// 8329.787 us; speedup vs baseline: 1.6806x; 1.6806x over previous
//
#include <hip/hip_runtime.h>
#include <hip/hip_bf16.h>

// TSGCN: GCN(2 layers, fused) -> GRU(4096->256) -> GRU(256->256) -> FC head
// B=32 S=512 N=64 F=16 G=64 H=256.
// R2: single-block-per-batch GRU with f16 weights (96 dwords in named uint4
// regs + 32 dwords/row in LDS), fp32 h and gate math via v_fma_mix pattern.

#define EPS_BN 1e-5f

typedef float f32x4 __attribute__((ext_vector_type(4)));
typedef _Float16 half2_t __attribute__((ext_vector_type(2)));

static __device__ __forceinline__ half2_t u2h(unsigned u) {
  return __builtin_bit_cast(half2_t, u);
}

// ------------------------------------------------- pack Whh (fp32 -> f16)
// Row r (gate-row of Whh, 0..767), chunk q (0..127) packs k=2q,2q+1.
// q<96  -> register part: wp[(i*768 + r)*4 + e], i=q/4, e=q%4  (uint4/thread)
// q>=96 -> LDS part:      wp[73728 + r*32 + (q-96)]
__global__ void k_pack_whh(const float* __restrict__ whh, unsigned* __restrict__ wp) {
  int idx = blockIdx.x * 256 + threadIdx.x;   // idx = r*128 + q
  if (idx >= 768 * 128) return;
  int r = idx >> 7, q = idx & 127;
  half2_t h = { (_Float16)whh[r * 256 + 2 * q], (_Float16)whh[r * 256 + 2 * q + 1] };
  unsigned u = __builtin_bit_cast(unsigned, h);
  if (q < 96) { int i = q >> 2, e = q & 3; wp[(i * 768 + r) * 4 + e] = u; }
  else        { wp[73728 + r * 32 + (q - 96)] = u; }
}

// ------------------------------------------------------------- fused GCN
__global__ __launch_bounds__(256) void k_gcn(
    const float* __restrict__ x, const float* __restrict__ adj,
    const float* __restrict__ W0, const float* __restrict__ b0,
    const float* __restrict__ W1, const float* __restrict__ b1,
    const float* __restrict__ bn_g, const float* __restrict__ bn_b,
    const float* __restrict__ bn_m, const float* __restrict__ bn_v,
    float* __restrict__ seq, int base)
{
  __shared__ float As[4096];
  __shared__ float Xs[1024];
  __shared__ float Hs[4096];
  __shared__ float Qs[4096];
  __shared__ float bnm_s[64], bns_s[64], bnb_s[64];

  const int t = threadIdx.x;
  const int lane = t & 63;
  const int w = t >> 6;
  const int m = base + blockIdx.x;

  {
    const float4* a4 = (const float4*)adj;
    float4* s4 = (float4*)As;
#pragma unroll
    for (int p = 0; p < 4; ++p) s4[t + 256 * p] = a4[t + 256 * p];
    ((float4*)Xs)[t] = ((const float4*)(x + (size_t)m * 1024))[t];
  }
  if (t < 64) {
    bns_s[t] = rsqrtf(bn_v[t] + EPS_BN) * bn_g[t];
    bnm_s[t] = bn_m[t];
    bnb_s[t] = bn_b[t];
  }
  float w0r[16];
#pragma unroll
  for (int f = 0; f < 16; ++f) w0r[f] = W0[f * 64 + lane];
  const float b0v = b0[lane], b1v = b1[lane];
  __syncthreads();

  float p[64];
#pragma unroll
  for (int v = 0; v < 64; ++v) {
    float acc = 0.f;
#pragma unroll
    for (int f = 0; f < 16; ++f) acc += Xs[v * 16 + f] * w0r[f];
    p[v] = acc;
  }
#pragma unroll
  for (int uu = 0; uu < 16; ++uu) {
    int u = w * 16 + uu;
    float acc = 0.f;
#pragma unroll
    for (int v = 0; v < 64; ++v) acc += As[u * 64 + v] * p[v];
    float h1 = fmaxf(acc + b0v, 0.f);
    h1 = (h1 - bnm_s[u]) * bns_s[u] + bnb_s[u];
    Hs[u * 64 + lane] = h1;
  }
  __syncthreads();
  float w1r[64];
#pragma unroll
  for (int f = 0; f < 64; ++f) w1r[f] = W1[f * 64 + lane];
#pragma unroll
  for (int vv = 0; vv < 16; ++vv) {
    int v = w * 16 + vv;
    float acc = 0.f;
#pragma unroll
    for (int f = 0; f < 64; ++f) acc += Hs[v * 64 + f] * w1r[f];
    Qs[v * 64 + lane] = acc;
  }
  __syncthreads();
  float q[64];
#pragma unroll
  for (int v = 0; v < 64; ++v) q[v] = Qs[v * 64 + lane];
  float* outrow = seq + (size_t)blockIdx.x * 4096;
#pragma unroll
  for (int uu = 0; uu < 16; ++uu) {
    int u = w * 16 + uu;
    float acc = 0.f;
#pragma unroll
    for (int v = 0; v < 64; ++v) acc += As[u * 64 + v] * q[v];
    outrow[u * 64 + lane] = fmaxf(acc + b1v, 0.f);
  }
}

// --------------------------------------------------------- GEMM  C = A@B^T + bias
#define BM 128
#define BN 128
#define BKK 16
__global__ __launch_bounds__(256) void k_gemm_nt(
    const float* __restrict__ A, int lda,
    const float* __restrict__ Bm,
    const float* __restrict__ bias,
    float* __restrict__ C,
    int K, int mBlocks)
{
  __shared__ float As[BKK][BM + 4];
  __shared__ float Bs[BKK][BN + 4];
  const int bid = blockIdx.x;
  const int mb = bid % mBlocks;
  const int nb = bid / mBlocks;
  const int m0 = mb * BM, n0 = nb * BN;
  const int t = threadIdx.x;
  const int tx = t & 15, ty = t >> 4;
  const int lr = t >> 2;
  const int lk = (t & 3) * 4;

  const float* Ap  = A  + (size_t)(m0 + lr) * lda + lk;
  const float* Ap2 = Ap + (size_t)64 * lda;
  const float* Bp  = Bm + (size_t)(n0 + lr) * K + lk;
  const float* Bp2 = Bp + (size_t)64 * K;

  float acc[8][8] = {};
  for (int kt = 0; kt < K; kt += BKK) {
    const float4 a0 = *(const float4*)(Ap + kt);
    const float4 a1 = *(const float4*)(Ap2 + kt);
    const float4 g0 = *(const float4*)(Bp + kt);
    const float4 g1 = *(const float4*)(Bp2 + kt);
    __syncthreads();
    As[lk + 0][lr] = a0.x; As[lk + 1][lr] = a0.y; As[lk + 2][lr] = a0.z; As[lk + 3][lr] = a0.w;
    As[lk + 0][64 + lr] = a1.x; As[lk + 1][64 + lr] = a1.y; As[lk + 2][64 + lr] = a1.z; As[lk + 3][64 + lr] = a1.w;
    Bs[lk + 0][lr] = g0.x; Bs[lk + 1][lr] = g0.y; Bs[lk + 2][lr] = g0.z; Bs[lk + 3][lr] = g0.w;
    Bs[lk + 0][64 + lr] = g1.x; Bs[lk + 1][64 + lr] = g1.y; Bs[lk + 2][64 + lr] = g1.z; Bs[lk + 3][64 + lr] = g1.w;
    __syncthreads();
#pragma unroll
    for (int k = 0; k < BKK; ++k) {
      const float4 av0 = *(const float4*)&As[k][ty * 8];
      const float4 av1 = *(const float4*)&As[k][ty * 8 + 4];
      const float4 bv0 = *(const float4*)&Bs[k][tx * 8];
      const float4 bv1 = *(const float4*)&Bs[k][tx * 8 + 4];
      const float a_[8] = {av0.x, av0.y, av0.z, av0.w, av1.x, av1.y, av1.z, av1.w};
      const float b_[8] = {bv0.x, bv0.y, bv0.z, bv0.w, bv1.x, bv1.y, bv1.z, bv1.w};
#pragma unroll
      for (int im = 0; im < 8; ++im)
#pragma unroll
        for (int jn = 0; jn < 8; ++jn)
          acc[im][jn] += a_[im] * b_[jn];
    }
  }
#pragma unroll
  for (int im = 0; im < 8; ++im) {
    const int mrow = m0 + ty * 8 + im;
    float* crow = C + (size_t)mrow * 768 + n0 + tx * 8;
#pragma unroll
    for (int jn = 0; jn < 8; ++jn)
      crow[jn] = acc[im][jn] + bias[n0 + tx * 8 + jn];
  }
}

// ------------------------------------------------------------------ GRU layer
// ONE block per batch, 768 threads. Thread t owns gate-row t of Whh:
//  - k=0..191 as f16 in 24 named uint4 regs (96 VGPRs, no array -> no scratch)
//  - k=192..255 as f16 in LDS (768 rows x 32 dwords, padded stride 34)
// Per step: fp32 dot via fma_mix ((float)f16 * f32), gh[t] -> barrier ->
// t<256 gate math in fp32 -> barrier. No cross-block sync.
__global__ __launch_bounds__(768, 3) void k_gru(
    const float* __restrict__ gi,        // [32*512][768]
    const unsigned* __restrict__ wp,     // packed f16 weights (see k_pack_whh)
    const float* __restrict__ bhh,       // [768]
    float* __restrict__ ys)              // [32*512][256]
{
  const int b = blockIdx.x;
  const int t = threadIdx.x;

  __shared__ float h_s[256];
  __shared__ float gh[768];
  __shared__ unsigned wlds[768 * 34];   // 104.4 KB, rows padded to 34 dwords

  const uint4* wp4 = (const uint4*)wp;
#define LW(i) const uint4 wr##i = wp4[(i) * 768 + t];
  LW(0) LW(1) LW(2) LW(3) LW(4) LW(5) LW(6) LW(7)
  LW(8) LW(9) LW(10) LW(11) LW(12) LW(13) LW(14) LW(15)
  LW(16) LW(17) LW(18) LW(19) LW(20) LW(21) LW(22) LW(23)
#undef LW

  // fill LDS weight slab: rows [768][32] -> padded [768][34]
  for (int idx = t; idx < 768 * 32; idx += 768) {
    int r = idx >> 5, c = idx & 31;
    wlds[r * 34 + c] = wp[73728 + idx];
  }

  float br = 0.f, bz = 0.f, bn = 0.f;
  if (t < 256) {
    br = bhh[t]; bz = bhh[256 + t]; bn = bhh[512 + t];
    h_s[t] = 0.f;
  }
  __syncthreads();

  const float* gib = gi + (size_t)b * 512 * 768;
  const f32x4* hs4 = (const f32x4*)h_s;
  const int wbase = t * 34;

#pragma unroll 1
  for (int step = 0; step < 512; ++step) {
    // issue gi loads early; latency hides under the dot
    float ir = 0.f, iz = 0.f, inn = 0.f;
    if (t < 256) {
      const float* g = gib + (size_t)step * 768;
      ir = g[t]; iz = g[256 + t]; inn = g[512 + t];
    }

    float acc = 0.f;
#define MREG(i) { \
    const f32x4 hA = hs4[2 * (i)], hB = hs4[2 * (i) + 1]; \
    const half2_t wa = u2h(wr##i.x), wb = u2h(wr##i.y); \
    const half2_t wc = u2h(wr##i.z), wd = u2h(wr##i.w); \
    acc = fmaf((float)wa[0], hA.x, acc); acc = fmaf((float)wa[1], hA.y, acc); \
    acc = fmaf((float)wb[0], hA.z, acc); acc = fmaf((float)wb[1], hA.w, acc); \
    acc = fmaf((float)wc[0], hB.x, acc); acc = fmaf((float)wc[1], hB.y, acc); \
    acc = fmaf((float)wd[0], hB.z, acc); acc = fmaf((float)wd[1], hB.w, acc); }
    MREG(0) MREG(1) MREG(2) MREG(3) MREG(4) MREG(5)
    MREG(6) MREG(7) MREG(8) MREG(9) MREG(10) MREG(11)
    MREG(12) MREG(13) MREG(14) MREG(15) MREG(16) MREG(17)
    MREG(18) MREG(19) MREG(20) MREG(21) MREG(22) MREG(23)
#undef MREG
#define MLDS(j) { \
    const uint2 wv = *(const uint2*)&wlds[wbase + 2 * (j)]; \
    const f32x4 hC = hs4[48 + (j)]; \
    const half2_t wa = u2h(wv.x), wb = u2h(wv.y); \
    acc = fmaf((float)wa[0], hC.x, acc); acc = fmaf((float)wa[1], hC.y, acc); \
    acc = fmaf((float)wb[0], hC.z, acc); acc = fmaf((float)wb[1], hC.w, acc); }
    MLDS(0) MLDS(1) MLDS(2) MLDS(3) MLDS(4) MLDS(5) MLDS(6) MLDS(7)
    MLDS(8) MLDS(9) MLDS(10) MLDS(11) MLDS(12) MLDS(13) MLDS(14) MLDS(15)
#undef MLDS

    gh[t] = acc;
    __syncthreads();

    if (t < 256) {
      const float hr = gh[t] + br;
      const float hz = gh[256 + t] + bz;
      const float hn = gh[512 + t] + bn;
      const float r = __builtin_amdgcn_rcpf(1.f + __expf(-(ir + hr)));
      const float z = __builtin_amdgcn_rcpf(1.f + __expf(-(iz + hz)));
      const float e2 = __expf(2.f * (inn + r * hn));
      const float n = 1.f - 2.f * __builtin_amdgcn_rcpf(e2 + 1.f);
      const float hnew = (1.f - z) * n + z * h_s[t];
      h_s[t] = hnew;
      ys[((size_t)b * 512 + step) * 256 + t] = hnew;
    }
    __syncthreads();
  }
}

// ------------------------------------------------------------------ FC head
__global__ __launch_bounds__(128) void k_head(
    const float* __restrict__ ys1,
    const float* __restrict__ fc1w, const float* __restrict__ fc1b,
    const float* __restrict__ fc2w, const float* __restrict__ fc2b,
    float* __restrict__ out)
{
  __shared__ float last[256];
  __shared__ float o1[128];
  const int b = blockIdx.x, t = threadIdx.x;
  const float* src = ys1 + (size_t)(b * 512 + 511) * 256;
  last[t] = src[t];
  last[128 + t] = src[128 + t];
  __syncthreads();
  float acc = fc1b[t];
#pragma unroll 8
  for (int k = 0; k < 256; ++k) acc += last[k] * fc1w[k * 128 + t];
  o1[t] = fmaxf(acc, 0.f);
  __syncthreads();
  if (t < 64) {
    float acc2 = fc2b[t];
#pragma unroll 8
    for (int i = 0; i < 128; ++i) acc2 += o1[i] * fc2w[i * 64 + t];
    out[b * 64 + t] = acc2;
  }
}

// ------------------------------------------------------------------ launcher
extern "C" void kernel_launch(void* const* d_in, const int* in_sizes, int n_in,
                              void* d_out, int out_size, void* d_ws, size_t ws_size,
                              hipStream_t stream)
{
  const float* x    = (const float*)d_in[0];
  const float* adj  = (const float*)d_in[1];
  const float* W0   = (const float*)d_in[2];
  const float* b0   = (const float*)d_in[3];
  const float* W1   = (const float*)d_in[4];
  const float* b1   = (const float*)d_in[5];
  const float* bng  = (const float*)d_in[6];
  const float* bnbb = (const float*)d_in[7];
  const float* bnm  = (const float*)d_in[8];
  const float* bnv  = (const float*)d_in[9];
  const float* Wih0 = (const float*)d_in[10];
  const float* Whh0 = (const float*)d_in[11];
  const float* bih0 = (const float*)d_in[12];
  const float* bhh0 = (const float*)d_in[13];
  const float* Wih1 = (const float*)d_in[14];
  const float* Whh1 = (const float*)d_in[15];
  const float* bih1 = (const float*)d_in[16];
  const float* bhh1 = (const float*)d_in[17];
  const float* fc1w = (const float*)d_in[18];
  const float* fc1b = (const float*)d_in[19];
  const float* fc2w = (const float*)d_in[20];
  const float* fc2b = (const float*)d_in[21];
  float* out = (float*)d_out;

  // workspace (floats): seqbuf(CHUNK*4096) | gi(16384*768) | ys0(16384*256)
  //                     | wp0(98304 u32) | wp1(98304 u32)
  float* ws = (float*)d_ws;
  const size_t fixed = (size_t)16384 * 768 + (size_t)16384 * 256 + 2 * 98304;
  int CHUNK = 16384;
  while (CHUNK > 128 && ((size_t)CHUNK * 4096 + fixed) * 4 > ws_size) CHUNK >>= 1;

  size_t off = 0;
  float* seqbuf = ws + off; off += (size_t)CHUNK * 4096;
  float* gi     = ws + off; off += (size_t)16384 * 768;
  float* ys0    = ws + off; off += (size_t)16384 * 256;
  unsigned* wp0 = (unsigned*)(ws + off); off += 98304;
  unsigned* wp1 = (unsigned*)(ws + off); off += 98304;
  float* ys1    = ys0;   // ys0 dead after gi1 GEMM -> reuse

  k_pack_whh<<<384, 256, 0, stream>>>(Whh0, wp0);
  k_pack_whh<<<384, 256, 0, stream>>>(Whh1, wp1);

  const int nChunks = 16384 / CHUNK;
  for (int ci = 0; ci < nChunks; ++ci) {
    const int base = ci * CHUNK;
    k_gcn<<<CHUNK, 256, 0, stream>>>(x, adj, W0, b0, W1, b1, bng, bnbb, bnm, bnv, seqbuf, base);
    const int mB = CHUNK / BM;
    k_gemm_nt<<<mB * 6, 256, 0, stream>>>(seqbuf, 4096, Wih0, bih0, gi + (size_t)base * 768, 4096, mB);
  }
  k_gru<<<32, 768, 0, stream>>>(gi, wp0, bhh0, ys0);
  k_gemm_nt<<<128 * 6, 256, 0, stream>>>(ys0, 256, Wih1, bih1, gi, 256, 128);
  k_gru<<<32, 768, 0, stream>>>(gi, wp1, bhh1, ys1);
  k_head<<<32, 128, 0, stream>>>(ys1, fc1w, fc1b, fc2w, fc2b, out);
}

// Round 5
// 3605.708 us; speedup vs baseline: 3.8825x; 2.3102x over previous
//
#include <hip/hip_runtime.h>
#include <hip/hip_bf16.h>

// TSGCN: GCN(2 layers, fused) -> GRU(4096->256) -> GRU(256->256) -> FC head
// B=32 S=512 N=64 F=16 G=64 H=256.
// R4 = R3 with s_nop spelled as inline asm (builtin doesn't exist).
// MFMA GRU: one block per batch (32 blocks, 512 thr). gh = Whh*h via
// v_mfma_f32_16x16x32_f16 with h replicated across A-rows; Whh fragments
// pinned in AGPRs via "a" inline-asm constraints (k-slices 0-5) + LDS (6-7).
// h state stays fp32; only MFMA operands are f16.

#define EPS_BN 1e-5f

typedef float f32x4 __attribute__((ext_vector_type(4)));
typedef unsigned u32x4v __attribute__((ext_vector_type(4)));

// ---------------------------------------------- pack Whh into MFMA B-fragments
// GRU wave w (0..7) owns outputs n in [96w, 96w+96) = 6 tiles of 16.
// Fragment (w, nt, ks): lane l holds 8 f16: Whh[n][k], n = 96w+16nt+(l&15),
// k = 32ks + 8*(l>>4) + j  (j=0..7; dword d packs j=2d lo, j=2d+1 hi).
// Stored at wp[((w*6+nt)*8+ks)*64 + l] (uint4), coalesced for the GRU load.
__global__ void k_pack_frag(const float* __restrict__ whh, uint4* __restrict__ wp) {
  int tid = blockIdx.x * 256 + threadIdx.x;
  if (tid >= 24576) return;
  int l = tid & 63;
  int rest = tid >> 6;
  int ks = rest & 7; rest >>= 3;
  int nt = rest % 6;
  int w  = rest / 6;
  int n  = w * 96 + nt * 16 + (l & 15);
  int kb = ks * 32 + (l >> 4) * 8;
  const float* src = whh + (size_t)n * 256 + kb;
  unsigned dw[4];
#pragma unroll
  for (int d = 0; d < 4; ++d) {
    unsigned short lo = __builtin_bit_cast(unsigned short, (_Float16)src[2 * d]);
    unsigned short hi = __builtin_bit_cast(unsigned short, (_Float16)src[2 * d + 1]);
    dw[d] = (unsigned)lo | ((unsigned)hi << 16);
  }
  wp[tid] = make_uint4(dw[0], dw[1], dw[2], dw[3]);
}

// ------------------------------------------------------------- fused GCN
__global__ __launch_bounds__(256) void k_gcn(
    const float* __restrict__ x, const float* __restrict__ adj,
    const float* __restrict__ W0, const float* __restrict__ b0,
    const float* __restrict__ W1, const float* __restrict__ b1,
    const float* __restrict__ bn_g, const float* __restrict__ bn_b,
    const float* __restrict__ bn_m, const float* __restrict__ bn_v,
    float* __restrict__ seq, int base)
{
  __shared__ float As[4096];
  __shared__ float Xs[1024];
  __shared__ float Hs[4096];
  __shared__ float Qs[4096];
  __shared__ float bnm_s[64], bns_s[64], bnb_s[64];

  const int t = threadIdx.x;
  const int lane = t & 63;
  const int w = t >> 6;
  const int m = base + blockIdx.x;

  {
    const float4* a4 = (const float4*)adj;
    float4* s4 = (float4*)As;
#pragma unroll
    for (int p = 0; p < 4; ++p) s4[t + 256 * p] = a4[t + 256 * p];
    ((float4*)Xs)[t] = ((const float4*)(x + (size_t)m * 1024))[t];
  }
  if (t < 64) {
    bns_s[t] = rsqrtf(bn_v[t] + EPS_BN) * bn_g[t];
    bnm_s[t] = bn_m[t];
    bnb_s[t] = bn_b[t];
  }
  float w0r[16];
#pragma unroll
  for (int f = 0; f < 16; ++f) w0r[f] = W0[f * 64 + lane];
  const float b0v = b0[lane], b1v = b1[lane];
  __syncthreads();

  float p[64];
#pragma unroll
  for (int v = 0; v < 64; ++v) {
    float acc = 0.f;
#pragma unroll
    for (int f = 0; f < 16; ++f) acc += Xs[v * 16 + f] * w0r[f];
    p[v] = acc;
  }
#pragma unroll
  for (int uu = 0; uu < 16; ++uu) {
    int u = w * 16 + uu;
    float acc = 0.f;
#pragma unroll
    for (int v = 0; v < 64; ++v) acc += As[u * 64 + v] * p[v];
    float h1 = fmaxf(acc + b0v, 0.f);
    h1 = (h1 - bnm_s[u]) * bns_s[u] + bnb_s[u];
    Hs[u * 64 + lane] = h1;
  }
  __syncthreads();
  float w1r[64];
#pragma unroll
  for (int f = 0; f < 64; ++f) w1r[f] = W1[f * 64 + lane];
#pragma unroll
  for (int vv = 0; vv < 16; ++vv) {
    int v = w * 16 + vv;
    float acc = 0.f;
#pragma unroll
    for (int f = 0; f < 64; ++f) acc += Hs[v * 64 + f] * w1r[f];
    Qs[v * 64 + lane] = acc;
  }
  __syncthreads();
  float q[64];
#pragma unroll
  for (int v = 0; v < 64; ++v) q[v] = Qs[v * 64 + lane];
  float* outrow = seq + (size_t)blockIdx.x * 4096;
#pragma unroll
  for (int uu = 0; uu < 16; ++uu) {
    int u = w * 16 + uu;
    float acc = 0.f;
#pragma unroll
    for (int v = 0; v < 64; ++v) acc += As[u * 64 + v] * q[v];
    outrow[u * 64 + lane] = fmaxf(acc + b1v, 0.f);
  }
}

// --------------------------------------------------------- GEMM  C = A@B^T + bias
#define BM 128
#define BN 128
#define BKK 16
__global__ __launch_bounds__(256) void k_gemm_nt(
    const float* __restrict__ A, int lda,
    const float* __restrict__ Bm,
    const float* __restrict__ bias,
    float* __restrict__ C,
    int K, int mBlocks)
{
  __shared__ float As[BKK][BM + 4];
  __shared__ float Bs[BKK][BN + 4];
  const int bid = blockIdx.x;
  const int mb = bid % mBlocks;
  const int nb = bid / mBlocks;
  const int m0 = mb * BM, n0 = nb * BN;
  const int t = threadIdx.x;
  const int tx = t & 15, ty = t >> 4;
  const int lr = t >> 2;
  const int lk = (t & 3) * 4;

  const float* Ap  = A  + (size_t)(m0 + lr) * lda + lk;
  const float* Ap2 = Ap + (size_t)64 * lda;
  const float* Bp  = Bm + (size_t)(n0 + lr) * K + lk;
  const float* Bp2 = Bp + (size_t)64 * K;

  float acc[8][8] = {};
  for (int kt = 0; kt < K; kt += BKK) {
    const float4 a0 = *(const float4*)(Ap + kt);
    const float4 a1 = *(const float4*)(Ap2 + kt);
    const float4 g0 = *(const float4*)(Bp + kt);
    const float4 g1 = *(const float4*)(Bp2 + kt);
    __syncthreads();
    As[lk + 0][lr] = a0.x; As[lk + 1][lr] = a0.y; As[lk + 2][lr] = a0.z; As[lk + 3][lr] = a0.w;
    As[lk + 0][64 + lr] = a1.x; As[lk + 1][64 + lr] = a1.y; As[lk + 2][64 + lr] = a1.z; As[lk + 3][64 + lr] = a1.w;
    Bs[lk + 0][lr] = g0.x; Bs[lk + 1][lr] = g0.y; Bs[lk + 2][lr] = g0.z; Bs[lk + 3][lr] = g0.w;
    Bs[lk + 0][64 + lr] = g1.x; Bs[lk + 1][64 + lr] = g1.y; Bs[lk + 2][64 + lr] = g1.z; Bs[lk + 3][64 + lr] = g1.w;
    __syncthreads();
#pragma unroll
    for (int k = 0; k < BKK; ++k) {
      const float4 av0 = *(const float4*)&As[k][ty * 8];
      const float4 av1 = *(const float4*)&As[k][ty * 8 + 4];
      const float4 bv0 = *(const float4*)&Bs[k][tx * 8];
      const float4 bv1 = *(const float4*)&Bs[k][tx * 8 + 4];
      const float a_[8] = {av0.x, av0.y, av0.z, av0.w, av1.x, av1.y, av1.z, av1.w};
      const float b_[8] = {bv0.x, bv0.y, bv0.z, bv0.w, bv1.x, bv1.y, bv1.z, bv1.w};
#pragma unroll
      for (int im = 0; im < 8; ++im)
#pragma unroll
        for (int jn = 0; jn < 8; ++jn)
          acc[im][jn] += a_[im] * b_[jn];
    }
  }
#pragma unroll
  for (int im = 0; im < 8; ++im) {
    const int mrow = m0 + ty * 8 + im;
    float* crow = C + (size_t)mrow * 768 + n0 + tx * 8;
#pragma unroll
    for (int jn = 0; jn < 8; ++jn)
      crow[jn] = acc[im][jn] + bias[n0 + tx * 8 + jn];
  }
}

// ------------------------------------------------------------------ GRU layer
// MFMA D = A*B + D : A = h broadcast to all 16 rows (f16), B = Whh^T fragment.
// B pinned in AGPRs ("a" constraint) for k-slices 0..5, LDS for 6..7.
#define MFMA_A(c, a, b) asm volatile("v_mfma_f32_16x16x32_f16 %0, %1, %2, %0" \
                                     : "+v"(c) : "v"(a), "a"(b))
#define MFMA_V(c, a, b) asm volatile("v_mfma_f32_16x16x32_f16 %0, %1, %2, %0" \
                                     : "+v"(c) : "v"(a), "v"(b))

__global__ __launch_bounds__(512, 2) void k_gru(
    const float* __restrict__ gi,        // [32*512][768]
    const uint4* __restrict__ wp,        // packed B-fragments (k_pack_frag)
    const float* __restrict__ bhh,       // [768]
    float* __restrict__ ys)              // [32*512][256]
{
  const int b = blockIdx.x;
  const int t = threadIdx.x;
  const int w = t >> 6;        // wave 0..7
  const int l = t & 63;

  __shared__ __align__(16) _Float16 h2[256];   // f16 copy of h
  __shared__ float h_s[256];                   // fp32 h state
  __shared__ float gh[768];
  __shared__ u32x4v blds[8][12][64];           // 96 KB: k-slices 6,7

  const u32x4v* wp4 = (const u32x4v*)wp;
  const int wbase = w * 6;

  // ---- load B-fragments: k-slices 0..5 -> named vars (forced AGPR by "a" use)
#define LBK(nt, ks) const u32x4v b##nt##_##ks = wp4[(((wbase + nt) * 8 + ks) << 6) + l];
#define LBNT(nt) LBK(nt,0) LBK(nt,1) LBK(nt,2) LBK(nt,3) LBK(nt,4) LBK(nt,5)
  LBNT(0) LBNT(1) LBNT(2) LBNT(3) LBNT(4) LBNT(5)
#undef LBNT
#undef LBK
  // ---- k-slices 6,7 -> LDS  (fi = (ks-6)*6 + nt)
#pragma unroll
  for (int nt = 0; nt < 6; ++nt) {
    blds[w][nt]     [l] = wp4[(((wbase + nt) * 8 + 6) << 6) + l];
    blds[w][6 + nt] [l] = wp4[(((wbase + nt) * 8 + 7) << 6) + l];
  }

  float br = 0.f, bz = 0.f, bn = 0.f;
  if (t < 256) {
    br = bhh[t]; bz = bhh[256 + t]; bn = bhh[512 + t];
    h_s[t] = 0.f;
    h2[t] = (_Float16)0.f;
  }
  __syncthreads();

  const float* gib = gi + (size_t)b * 512 * 768;
  const char* h2c = (const char*)h2;
  const int g16 = (l >> 4) * 16;

#pragma unroll 1
  for (int step = 0; step < 512; ++step) {
    // prefetch gi for this step (consumed after the barrier)
    float ir = 0.f, iz = 0.f, inn = 0.f;
    if (t < 256) {
      const float* g = gib + (size_t)step * 768;
      ir = g[t]; iz = g[256 + t]; inn = g[512 + t];
    }

    f32x4 c0 = {0.f,0.f,0.f,0.f}, c1 = c0, c2 = c0, c3 = c0, c4 = c0, c5 = c0;

#define DOT_KS(ks) { \
    const u32x4v a = *(const u32x4v*)(h2c + (ks) * 64 + g16); \
    MFMA_A(c0, a, b0_##ks); MFMA_A(c1, a, b1_##ks); MFMA_A(c2, a, b2_##ks); \
    MFMA_A(c3, a, b3_##ks); MFMA_A(c4, a, b4_##ks); MFMA_A(c5, a, b5_##ks); }
    DOT_KS(0) DOT_KS(1) DOT_KS(2) DOT_KS(3) DOT_KS(4) DOT_KS(5)
#undef DOT_KS
    {
      const u32x4v a6 = *(const u32x4v*)(h2c + 6 * 64 + g16);
      MFMA_V(c0, a6, blds[w][0][l]); MFMA_V(c1, a6, blds[w][1][l]);
      MFMA_V(c2, a6, blds[w][2][l]); MFMA_V(c3, a6, blds[w][3][l]);
      MFMA_V(c4, a6, blds[w][4][l]); MFMA_V(c5, a6, blds[w][5][l]);
      const u32x4v a7 = *(const u32x4v*)(h2c + 7 * 64 + g16);
      MFMA_V(c0, a7, blds[w][6][l]);  MFMA_V(c1, a7, blds[w][7][l]);
      MFMA_V(c2, a7, blds[w][8][l]);  MFMA_V(c3, a7, blds[w][9][l]);
      MFMA_V(c4, a7, blds[w][10][l]); MFMA_V(c5, a7, blds[w][11][l]);
    }
    // MFMA-write -> VALU-read hazard guard (asm defs are opaque to compiler)
    asm volatile("s_nop 7\n\ts_nop 7");
    // all result rows identical (A rows replicated); lanes 0..15 hold col=l
    if (l < 16) {
      float* ghw = gh + w * 96 + l;
      ghw[0]  = c0.x; ghw[16] = c1.x; ghw[32] = c2.x;
      ghw[48] = c3.x; ghw[64] = c4.x; ghw[80] = c5.x;
    }
    __syncthreads();

    if (t < 256) {
      const float hr = gh[t] + br;
      const float hz = gh[256 + t] + bz;
      const float hn = gh[512 + t] + bn;
      const float r = __builtin_amdgcn_rcpf(1.f + __expf(-(ir + hr)));
      const float z = __builtin_amdgcn_rcpf(1.f + __expf(-(iz + hz)));
      const float e2 = __expf(2.f * (inn + r * hn));
      const float n = 1.f - 2.f * __builtin_amdgcn_rcpf(e2 + 1.f);
      const float hnew = (1.f - z) * n + z * h_s[t];
      h_s[t] = hnew;
      h2[t] = (_Float16)hnew;
      ys[((size_t)b * 512 + step) * 256 + t] = hnew;
    }
    __syncthreads();
  }
}

// ------------------------------------------------------------------ FC head
__global__ __launch_bounds__(128) void k_head(
    const float* __restrict__ ys1,
    const float* __restrict__ fc1w, const float* __restrict__ fc1b,
    const float* __restrict__ fc2w, const float* __restrict__ fc2b,
    float* __restrict__ out)
{
  __shared__ float last[256];
  __shared__ float o1[128];
  const int b = blockIdx.x, t = threadIdx.x;
  const float* src = ys1 + (size_t)(b * 512 + 511) * 256;
  last[t] = src[t];
  last[128 + t] = src[128 + t];
  __syncthreads();
  float acc = fc1b[t];
#pragma unroll 8
  for (int k = 0; k < 256; ++k) acc += last[k] * fc1w[k * 128 + t];
  o1[t] = fmaxf(acc, 0.f);
  __syncthreads();
  if (t < 64) {
    float acc2 = fc2b[t];
#pragma unroll 8
    for (int i = 0; i < 128; ++i) acc2 += o1[i] * fc2w[i * 64 + t];
    out[b * 64 + t] = acc2;
  }
}

// ------------------------------------------------------------------ launcher
extern "C" void kernel_launch(void* const* d_in, const int* in_sizes, int n_in,
                              void* d_out, int out_size, void* d_ws, size_t ws_size,
                              hipStream_t stream)
{
  const float* x    = (const float*)d_in[0];
  const float* adj  = (const float*)d_in[1];
  const float* W0   = (const float*)d_in[2];
  const float* b0   = (const float*)d_in[3];
  const float* W1   = (const float*)d_in[4];
  const float* b1   = (const float*)d_in[5];
  const float* bng  = (const float*)d_in[6];
  const float* bnbb = (const float*)d_in[7];
  const float* bnm  = (const float*)d_in[8];
  const float* bnv  = (const float*)d_in[9];
  const float* Wih0 = (const float*)d_in[10];
  const float* Whh0 = (const float*)d_in[11];
  const float* bih0 = (const float*)d_in[12];
  const float* bhh0 = (const float*)d_in[13];
  const float* Wih1 = (const float*)d_in[14];
  const float* Whh1 = (const float*)d_in[15];
  const float* bih1 = (const float*)d_in[16];
  const float* bhh1 = (const float*)d_in[17];
  const float* fc1w = (const float*)d_in[18];
  const float* fc1b = (const float*)d_in[19];
  const float* fc2w = (const float*)d_in[20];
  const float* fc2b = (const float*)d_in[21];
  float* out = (float*)d_out;

  // workspace (floats): seqbuf(CHUNK*4096) | gi(16384*768) | ys0(16384*256)
  //                     | wp0(98304 dw) | wp1(98304 dw)
  float* ws = (float*)d_ws;
  const size_t fixed = (size_t)16384 * 768 + (size_t)16384 * 256 + 2 * 98304;
  int CHUNK = 16384;
  while (CHUNK > 128 && ((size_t)CHUNK * 4096 + fixed) * 4 > ws_size) CHUNK >>= 1;

  size_t off = 0;
  float* seqbuf = ws + off; off += (size_t)CHUNK * 4096;
  float* gi     = ws + off; off += (size_t)16384 * 768;
  float* ys0    = ws + off; off += (size_t)16384 * 256;
  uint4* wp0    = (uint4*)(ws + off); off += 98304;
  uint4* wp1    = (uint4*)(ws + off); off += 98304;
  float* ys1    = ys0;   // ys0 dead after gi1 GEMM -> reuse

  k_pack_frag<<<96, 256, 0, stream>>>(Whh0, wp0);
  k_pack_frag<<<96, 256, 0, stream>>>(Whh1, wp1);

  const int nChunks = 16384 / CHUNK;
  for (int ci = 0; ci < nChunks; ++ci) {
    const int base = ci * CHUNK;
    k_gcn<<<CHUNK, 256, 0, stream>>>(x, adj, W0, b0, W1, b1, bng, bnbb, bnm, bnv, seqbuf, base);
    const int mB = CHUNK / BM;
    k_gemm_nt<<<mB * 6, 256, 0, stream>>>(seqbuf, 4096, Wih0, bih0, gi + (size_t)base * 768, 4096, mB);
  }
  k_gru<<<32, 512, 0, stream>>>(gi, wp0, bhh0, ys0);
  k_gemm_nt<<<128 * 6, 256, 0, stream>>>(ys0, 256, Wih1, bih1, gi, 256, 128);
  k_gru<<<32, 512, 0, stream>>>(gi, wp1, bhh1, ys1);
  k_head<<<32, 128, 0, stream>>>(ys1, fc1w, fc1b, fc2w, fc2b, out);
}

// Round 6
// 3064.340 us; speedup vs baseline: 4.5684x; 1.1767x over previous
//
#include <hip/hip_runtime.h>
#include <hip/hip_bf16.h>

// TSGCN: GCN(2 layers, fused) -> GRU(4096->256) -> GRU(256->256) -> FC head
// B=32 S=512 N=64 F=16 G=64 H=256.
// R6: gi GEMMs -> f16 MFMA with exact hi/lo 3-term split (fp32 accuracy),
// LDS-free (fragments straight from global). GCN emits seq as f16 hi/lo;
// GRU emits ys as f16 hi/lo for the gi1 GEMM. GRU core unchanged from R5.

#define EPS_BN 1e-5f

typedef float f32x4 __attribute__((ext_vector_type(4)));
typedef unsigned u32x4v __attribute__((ext_vector_type(4)));

// ---------------------------------------------------- fp32 -> f16 hi/lo split
__global__ void k_split16(const float* __restrict__ src,
                          _Float16* __restrict__ hi, _Float16* __restrict__ lo,
                          int n) {
  int i = blockIdx.x * 256 + threadIdx.x;
  if (i >= n) return;
  float v = src[i];
  _Float16 h = (_Float16)v;
  hi[i] = h;
  lo[i] = (_Float16)(v - (float)h);
}

// ---------------------------------------------- pack Whh into MFMA B-fragments
// (unchanged from R5 — proven layout) wave w owns n in [96w,96w+96);
// fragment (w,nt,ks): lane l holds Whh[n][k], n=96w+16nt+(l&15), k=32ks+8(l>>4)+j
__global__ void k_pack_frag(const float* __restrict__ whh, uint4* __restrict__ wp) {
  int tid = blockIdx.x * 256 + threadIdx.x;
  if (tid >= 24576) return;
  int l = tid & 63;
  int rest = tid >> 6;
  int ks = rest & 7; rest >>= 3;
  int nt = rest % 6;
  int w  = rest / 6;
  int n  = w * 96 + nt * 16 + (l & 15);
  int kb = ks * 32 + (l >> 4) * 8;
  const float* src = whh + (size_t)n * 256 + kb;
  unsigned dw[4];
#pragma unroll
  for (int d = 0; d < 4; ++d) {
    unsigned short lo = __builtin_bit_cast(unsigned short, (_Float16)src[2 * d]);
    unsigned short hi = __builtin_bit_cast(unsigned short, (_Float16)src[2 * d + 1]);
    dw[d] = (unsigned)lo | ((unsigned)hi << 16);
  }
  wp[tid] = make_uint4(dw[0], dw[1], dw[2], dw[3]);
}

// ------------------------------------------------------------- fused GCN
// One block per (b,s). Output row written as f16 hi/lo (exact split).
__global__ __launch_bounds__(256) void k_gcn(
    const float* __restrict__ x, const float* __restrict__ adj,
    const float* __restrict__ W0, const float* __restrict__ b0,
    const float* __restrict__ W1, const float* __restrict__ b1,
    const float* __restrict__ bn_g, const float* __restrict__ bn_b,
    const float* __restrict__ bn_m, const float* __restrict__ bn_v,
    _Float16* __restrict__ seqh, _Float16* __restrict__ seql, int base)
{
  __shared__ float As[4096];
  __shared__ float Xs[1024];
  __shared__ float Hs[4096];
  __shared__ float Qs[4096];
  __shared__ float bnm_s[64], bns_s[64], bnb_s[64];

  const int t = threadIdx.x;
  const int lane = t & 63;
  const int w = t >> 6;
  const int m = base + blockIdx.x;

  {
    const float4* a4 = (const float4*)adj;
    float4* s4 = (float4*)As;
#pragma unroll
    for (int p = 0; p < 4; ++p) s4[t + 256 * p] = a4[t + 256 * p];
    ((float4*)Xs)[t] = ((const float4*)(x + (size_t)m * 1024))[t];
  }
  if (t < 64) {
    bns_s[t] = rsqrtf(bn_v[t] + EPS_BN) * bn_g[t];
    bnm_s[t] = bn_m[t];
    bnb_s[t] = bn_b[t];
  }
  float w0r[16];
#pragma unroll
  for (int f = 0; f < 16; ++f) w0r[f] = W0[f * 64 + lane];
  const float b0v = b0[lane], b1v = b1[lane];
  __syncthreads();

  float p[64];
#pragma unroll
  for (int v = 0; v < 64; ++v) {
    float acc = 0.f;
#pragma unroll
    for (int f = 0; f < 16; ++f) acc += Xs[v * 16 + f] * w0r[f];
    p[v] = acc;
  }
#pragma unroll
  for (int uu = 0; uu < 16; ++uu) {
    int u = w * 16 + uu;
    float acc = 0.f;
#pragma unroll
    for (int v = 0; v < 64; ++v) acc += As[u * 64 + v] * p[v];
    float h1 = fmaxf(acc + b0v, 0.f);
    h1 = (h1 - bnm_s[u]) * bns_s[u] + bnb_s[u];
    Hs[u * 64 + lane] = h1;
  }
  __syncthreads();
  float w1r[64];
#pragma unroll
  for (int f = 0; f < 64; ++f) w1r[f] = W1[f * 64 + lane];
#pragma unroll
  for (int vv = 0; vv < 16; ++vv) {
    int v = w * 16 + vv;
    float acc = 0.f;
#pragma unroll
    for (int f = 0; f < 64; ++f) acc += Hs[v * 64 + f] * w1r[f];
    Qs[v * 64 + lane] = acc;
  }
  __syncthreads();
  float q[64];
#pragma unroll
  for (int v = 0; v < 64; ++v) q[v] = Qs[v * 64 + lane];
  _Float16* oh = seqh + (size_t)blockIdx.x * 4096;
  _Float16* ol = seql + (size_t)blockIdx.x * 4096;
#pragma unroll
  for (int uu = 0; uu < 16; ++uu) {
    int u = w * 16 + uu;
    float acc = 0.f;
#pragma unroll
    for (int v = 0; v < 64; ++v) acc += As[u * 64 + v] * q[v];
    float val = fmaxf(acc + b1v, 0.f);
    _Float16 hv = (_Float16)val;
    oh[u * 64 + lane] = hv;
    ol[u * 64 + lane] = (_Float16)(val - (float)hv);
  }
}

// ----------------------------------------------- MFMA GEMM  C = A@B^T + bias
// A: [M][K] f16 hi/lo, B: [768][K] f16 hi/lo, C: [M][768] fp32.
// 3-term split: C = Ah*Bh + Al*Bh + Ah*Bl  (error ~2^-22, fp32-grade).
// LDS-free: fragments loaded straight from global (A streams, B stays L2-hot).
// Fragment layout (on-device verified via R5 GRU): lane l holds row/col l&15,
// k = kt + (l>>4)*8 + j (8 contiguous f16 = one 16B load).
#define MFMA_VV(c, a, b) asm volatile("v_mfma_f32_16x16x32_f16 %0, %1, %2, %0" \
                                      : "+v"(c) : "v"(a), "v"(b))

__global__ __launch_bounds__(256, 2) void k_gemm_mfma(
    const _Float16* __restrict__ Ah, const _Float16* __restrict__ Al,
    const _Float16* __restrict__ Bh, const _Float16* __restrict__ Bl,
    const float* __restrict__ bias,
    float* __restrict__ C,
    int K, int mBlocks)
{
  const int bid = blockIdx.x;
  const int mb = bid % mBlocks;
  const int nb = bid / mBlocks;
  const int t = threadIdx.x;
  const int w = t >> 6, l = t & 63;
  const int m0 = mb * 128 + (w >> 1) * 64;
  const int n0 = nb * 128 + (w & 1) * 64;
  const int row = l & 15;
  const int kk = (l >> 4) * 8;

  const _Float16* ah = Ah + (size_t)(m0 + row) * K + kk;
  const _Float16* al = Al + (size_t)(m0 + row) * K + kk;
  const _Float16* bh = Bh + (size_t)(n0 + row) * K + kk;
  const _Float16* bl = Bl + (size_t)(n0 + row) * K + kk;

  f32x4 acc[4][4] = {};

  for (int kt = 0; kt < K; kt += 32) {
    u32x4v af_h[4], af_l[4], bf_h[4], bf_l[4];
#pragma unroll
    for (int i = 0; i < 4; ++i) {
      const size_t o = (size_t)(16 * i) * K + kt;
      af_h[i] = *(const u32x4v*)(ah + o);
      af_l[i] = *(const u32x4v*)(al + o);
      bf_h[i] = *(const u32x4v*)(bh + o);
      bf_l[i] = *(const u32x4v*)(bl + o);
    }
#pragma unroll
    for (int mi = 0; mi < 4; ++mi)
#pragma unroll
      for (int ni = 0; ni < 4; ++ni) {
        MFMA_VV(acc[mi][ni], af_h[mi], bf_h[ni]);
        MFMA_VV(acc[mi][ni], af_l[mi], bf_h[ni]);
        MFMA_VV(acc[mi][ni], af_h[mi], bf_l[ni]);
      }
  }

  // MFMA-write -> VALU-read hazard guard (asm defs are opaque to compiler)
  asm volatile("s_nop 7\n\ts_nop 7");

  const int r4 = (l >> 4) * 4;
#pragma unroll
  for (int ni = 0; ni < 4; ++ni) {
    const float bv = bias[n0 + 16 * ni + row];
#pragma unroll
    for (int mi = 0; mi < 4; ++mi) {
      float* cp = C + (size_t)(m0 + 16 * mi + r4) * 768 + n0 + 16 * ni + row;
      cp[0]    = acc[mi][ni].x + bv;
      cp[768]  = acc[mi][ni].y + bv;
      cp[1536] = acc[mi][ni].z + bv;
      cp[2304] = acc[mi][ni].w + bv;
    }
  }
}

// ------------------------------------------------------------------ GRU layer
// (R5 structure, unchanged) + ys written additionally as f16 hi/lo for the
// downstream MFMA GEMM.
#define MFMA_A(c, a, b) asm volatile("v_mfma_f32_16x16x32_f16 %0, %1, %2, %0" \
                                     : "+v"(c) : "v"(a), "a"(b))
#define MFMA_V(c, a, b) asm volatile("v_mfma_f32_16x16x32_f16 %0, %1, %2, %0" \
                                     : "+v"(c) : "v"(a), "v"(b))

__global__ __launch_bounds__(512, 2) void k_gru(
    const float* __restrict__ gi,        // [32*512][768]
    const uint4* __restrict__ wp,        // packed B-fragments (k_pack_frag)
    const float* __restrict__ bhh,       // [768]
    float* __restrict__ ys,              // [32*512][256] fp32
    _Float16* __restrict__ ysh,          // [32*512][256] f16 hi
    _Float16* __restrict__ ysl)          // [32*512][256] f16 lo
{
  const int b = blockIdx.x;
  const int t = threadIdx.x;
  const int w = t >> 6;        // wave 0..7
  const int l = t & 63;

  __shared__ __align__(16) _Float16 h2[256];   // f16 copy of h
  __shared__ float h_s[256];                   // fp32 h state
  __shared__ float gh[768];
  __shared__ u32x4v blds[8][12][64];           // 96 KB: k-slices 6,7

  const u32x4v* wp4 = (const u32x4v*)wp;
  const int wbase = w * 6;

#define LBK(nt, ks) const u32x4v b##nt##_##ks = wp4[(((wbase + nt) * 8 + ks) << 6) + l];
#define LBNT(nt) LBK(nt,0) LBK(nt,1) LBK(nt,2) LBK(nt,3) LBK(nt,4) LBK(nt,5)
  LBNT(0) LBNT(1) LBNT(2) LBNT(3) LBNT(4) LBNT(5)
#undef LBNT
#undef LBK
#pragma unroll
  for (int nt = 0; nt < 6; ++nt) {
    blds[w][nt]    [l] = wp4[(((wbase + nt) * 8 + 6) << 6) + l];
    blds[w][6 + nt][l] = wp4[(((wbase + nt) * 8 + 7) << 6) + l];
  }

  float br = 0.f, bz = 0.f, bn = 0.f;
  if (t < 256) {
    br = bhh[t]; bz = bhh[256 + t]; bn = bhh[512 + t];
    h_s[t] = 0.f;
    h2[t] = (_Float16)0.f;
  }
  __syncthreads();

  const float* gib = gi + (size_t)b * 512 * 768;
  const char* h2c = (const char*)h2;
  const int g16 = (l >> 4) * 16;

#pragma unroll 1
  for (int step = 0; step < 512; ++step) {
    float ir = 0.f, iz = 0.f, inn = 0.f;
    if (t < 256) {
      const float* g = gib + (size_t)step * 768;
      ir = g[t]; iz = g[256 + t]; inn = g[512 + t];
    }

    f32x4 c0 = {0.f,0.f,0.f,0.f}, c1 = c0, c2 = c0, c3 = c0, c4 = c0, c5 = c0;

#define DOT_KS(ks) { \
    const u32x4v a = *(const u32x4v*)(h2c + (ks) * 64 + g16); \
    MFMA_A(c0, a, b0_##ks); MFMA_A(c1, a, b1_##ks); MFMA_A(c2, a, b2_##ks); \
    MFMA_A(c3, a, b3_##ks); MFMA_A(c4, a, b4_##ks); MFMA_A(c5, a, b5_##ks); }
    DOT_KS(0) DOT_KS(1) DOT_KS(2) DOT_KS(3) DOT_KS(4) DOT_KS(5)
#undef DOT_KS
    {
      const u32x4v a6 = *(const u32x4v*)(h2c + 6 * 64 + g16);
      MFMA_V(c0, a6, blds[w][0][l]); MFMA_V(c1, a6, blds[w][1][l]);
      MFMA_V(c2, a6, blds[w][2][l]); MFMA_V(c3, a6, blds[w][3][l]);
      MFMA_V(c4, a6, blds[w][4][l]); MFMA_V(c5, a6, blds[w][5][l]);
      const u32x4v a7 = *(const u32x4v*)(h2c + 7 * 64 + g16);
      MFMA_V(c0, a7, blds[w][6][l]);  MFMA_V(c1, a7, blds[w][7][l]);
      MFMA_V(c2, a7, blds[w][8][l]);  MFMA_V(c3, a7, blds[w][9][l]);
      MFMA_V(c4, a7, blds[w][10][l]); MFMA_V(c5, a7, blds[w][11][l]);
    }
    asm volatile("s_nop 7\n\ts_nop 7");
    if (l < 16) {
      float* ghw = gh + w * 96 + l;
      ghw[0]  = c0.x; ghw[16] = c1.x; ghw[32] = c2.x;
      ghw[48] = c3.x; ghw[64] = c4.x; ghw[80] = c5.x;
    }
    __syncthreads();

    if (t < 256) {
      const float hr = gh[t] + br;
      const float hz = gh[256 + t] + bz;
      const float hn = gh[512 + t] + bn;
      const float r = __builtin_amdgcn_rcpf(1.f + __expf(-(ir + hr)));
      const float z = __builtin_amdgcn_rcpf(1.f + __expf(-(iz + hz)));
      const float e2 = __expf(2.f * (inn + r * hn));
      const float n = 1.f - 2.f * __builtin_amdgcn_rcpf(e2 + 1.f);
      const float hnew = (1.f - z) * n + z * h_s[t];
      h_s[t] = hnew;
      h2[t] = (_Float16)hnew;
      const size_t rowi = (size_t)b * 512 + step;
      ys[rowi * 256 + t] = hnew;
      const _Float16 hh = (_Float16)hnew;
      ysh[rowi * 256 + t] = hh;
      ysl[rowi * 256 + t] = (_Float16)(hnew - (float)hh);
    }
    __syncthreads();
  }
}

// ------------------------------------------------------------------ FC head
__global__ __launch_bounds__(128) void k_head(
    const float* __restrict__ ys1,
    const float* __restrict__ fc1w, const float* __restrict__ fc1b,
    const float* __restrict__ fc2w, const float* __restrict__ fc2b,
    float* __restrict__ out)
{
  __shared__ float last[256];
  __shared__ float o1[128];
  const int b = blockIdx.x, t = threadIdx.x;
  const float* src = ys1 + (size_t)(b * 512 + 511) * 256;
  last[t] = src[t];
  last[128 + t] = src[128 + t];
  __syncthreads();
  float acc = fc1b[t];
#pragma unroll 8
  for (int k = 0; k < 256; ++k) acc += last[k] * fc1w[k * 128 + t];
  o1[t] = fmaxf(acc, 0.f);
  __syncthreads();
  if (t < 64) {
    float acc2 = fc2b[t];
#pragma unroll 8
    for (int i = 0; i < 128; ++i) acc2 += o1[i] * fc2w[i * 64 + t];
    out[b * 64 + t] = acc2;
  }
}

// ------------------------------------------------------------------ launcher
extern "C" void kernel_launch(void* const* d_in, const int* in_sizes, int n_in,
                              void* d_out, int out_size, void* d_ws, size_t ws_size,
                              hipStream_t stream)
{
  const float* x    = (const float*)d_in[0];
  const float* adj  = (const float*)d_in[1];
  const float* W0   = (const float*)d_in[2];
  const float* b0   = (const float*)d_in[3];
  const float* W1   = (const float*)d_in[4];
  const float* b1   = (const float*)d_in[5];
  const float* bng  = (const float*)d_in[6];
  const float* bnbb = (const float*)d_in[7];
  const float* bnm  = (const float*)d_in[8];
  const float* bnv  = (const float*)d_in[9];
  const float* Wih0 = (const float*)d_in[10];
  const float* Whh0 = (const float*)d_in[11];
  const float* bih0 = (const float*)d_in[12];
  const float* bhh0 = (const float*)d_in[13];
  const float* Wih1 = (const float*)d_in[14];
  const float* Whh1 = (const float*)d_in[15];
  const float* bih1 = (const float*)d_in[16];
  const float* bhh1 = (const float*)d_in[17];
  const float* fc1w = (const float*)d_in[18];
  const float* fc1b = (const float*)d_in[19];
  const float* fc2w = (const float*)d_in[20];
  const float* fc2b = (const float*)d_in[21];
  float* out = (float*)d_out;

  // workspace (float units):
  // seqh+seql (CHUNK*4096 floats total) | gi 12.6M | ys0 4.2M | ysh 2.1M |
  // ysl 2.1M | wp0/wp1 98304 ea | bh0/bl0 1.57M ea | bh1/bl1 98304 ea
  float* ws = (float*)d_ws;
  const size_t fixed = (size_t)16384 * 768 + (size_t)16384 * 256
                     + 2 * ((size_t)16384 * 128)
                     + 2 * 98304
                     + 2 * ((size_t)768 * 4096 / 2)
                     + 2 * ((size_t)768 * 256 / 2);
  int CHUNK = 16384;
  while (CHUNK > 128 && ((size_t)CHUNK * 4096 + fixed) * 4 > ws_size) CHUNK >>= 1;

  size_t off = 0;
  _Float16* seqh = (_Float16*)(ws + off); off += (size_t)CHUNK * 2048;
  _Float16* seql = (_Float16*)(ws + off); off += (size_t)CHUNK * 2048;
  float* gi      = ws + off; off += (size_t)16384 * 768;
  float* ys0     = ws + off; off += (size_t)16384 * 256;
  _Float16* ysh  = (_Float16*)(ws + off); off += (size_t)16384 * 128;
  _Float16* ysl  = (_Float16*)(ws + off); off += (size_t)16384 * 128;
  uint4* wp0     = (uint4*)(ws + off); off += 98304;
  uint4* wp1     = (uint4*)(ws + off); off += 98304;
  _Float16* bh0  = (_Float16*)(ws + off); off += (size_t)768 * 2048;
  _Float16* bl0  = (_Float16*)(ws + off); off += (size_t)768 * 2048;
  _Float16* bh1  = (_Float16*)(ws + off); off += (size_t)768 * 128;
  _Float16* bl1  = (_Float16*)(ws + off); off += (size_t)768 * 128;
  float* ys1     = ys0;   // ys0 fp32 dead after gi1 GEMM -> reuse for layer 1

  k_pack_frag<<<96, 256, 0, stream>>>(Whh0, wp0);
  k_pack_frag<<<96, 256, 0, stream>>>(Whh1, wp1);
  k_split16<<<(3145728 + 255) / 256, 256, 0, stream>>>(Wih0, bh0, bl0, 3145728);
  k_split16<<<(196608 + 255) / 256, 256, 0, stream>>>(Wih1, bh1, bl1, 196608);

  const int nChunks = 16384 / CHUNK;
  for (int ci = 0; ci < nChunks; ++ci) {
    const int base = ci * CHUNK;
    k_gcn<<<CHUNK, 256, 0, stream>>>(x, adj, W0, b0, W1, b1, bng, bnbb, bnm, bnv,
                                     seqh, seql, base);
    const int mB = CHUNK / 128;
    k_gemm_mfma<<<mB * 6, 256, 0, stream>>>(seqh, seql, bh0, bl0, bih0,
                                            gi + (size_t)base * 768, 4096, mB);
  }
  k_gru<<<32, 512, 0, stream>>>(gi, wp0, bhh0, ys0, ysh, ysl);
  k_gemm_mfma<<<128 * 6, 256, 0, stream>>>(ysh, ysl, bh1, bl1, bih1, gi, 256, 128);
  k_gru<<<32, 512, 0, stream>>>(gi, wp1, bhh1, ys1, ysh, ysl);
  k_head<<<32, 128, 0, stream>>>(ys1, fc1w, fc1b, fc2w, fc2b, out);
}

// Round 7
// 2898.666 us; speedup vs baseline: 4.8295x; 1.0572x over previous
//
#include <hip/hip_runtime.h>
#include <hip/hip_bf16.h>

// TSGCN: GCN(2 layers, fused) -> GRU(4096->256) -> GRU(256->256) -> FC head
// B=32 S=512 N=64 F=16 G=64 H=256.
// R7: GRU restructured — wave-local gates. Wave w owns tiles {w,w+8,..,w+40}
// so r/z/n for outputs j=16w+(l&15)+128*(l>>4) land in that wave's own
// accumulators; gate math is in-register (no gh LDS round trip), h_old in
// VGPR, h2 f16 broadcast double-buffered -> ONE barrier per step.

#define EPS_BN 1e-5f

typedef float f32x4 __attribute__((ext_vector_type(4)));
typedef unsigned u32x4v __attribute__((ext_vector_type(4)));

// ---------------------------------------------------- fp32 -> f16 hi/lo split
__global__ void k_split16(const float* __restrict__ src,
                          _Float16* __restrict__ hi, _Float16* __restrict__ lo,
                          int n) {
  int i = blockIdx.x * 256 + threadIdx.x;
  if (i >= n) return;
  float v = src[i];
  _Float16 h = (_Float16)v;
  hi[i] = h;
  lo[i] = (_Float16)(v - (float)h);
}

// ---------------------------------------------- pack Whh into MFMA B-fragments
// R7 tile map: fragment (w, nt, ks) covers n-tile (w + 8*nt):
//   n = 16*w + 128*nt + (l&15), k = 32*ks + 8*(l>>4) + j.
// Storage order unchanged: wp[((w*6+nt)*8+ks)*64 + l] (uint4).
__global__ void k_pack_frag(const float* __restrict__ whh, uint4* __restrict__ wp) {
  int tid = blockIdx.x * 256 + threadIdx.x;
  if (tid >= 24576) return;
  int l = tid & 63;
  int rest = tid >> 6;
  int ks = rest & 7; rest >>= 3;
  int nt = rest % 6;
  int w  = rest / 6;
  int n  = 16 * w + 128 * nt + (l & 15);
  int kb = ks * 32 + (l >> 4) * 8;
  const float* src = whh + (size_t)n * 256 + kb;
  unsigned dw[4];
#pragma unroll
  for (int d = 0; d < 4; ++d) {
    unsigned short lo = __builtin_bit_cast(unsigned short, (_Float16)src[2 * d]);
    unsigned short hi = __builtin_bit_cast(unsigned short, (_Float16)src[2 * d + 1]);
    dw[d] = (unsigned)lo | ((unsigned)hi << 16);
  }
  wp[tid] = make_uint4(dw[0], dw[1], dw[2], dw[3]);
}

// ------------------------------------------------------------- fused GCN
__global__ __launch_bounds__(256) void k_gcn(
    const float* __restrict__ x, const float* __restrict__ adj,
    const float* __restrict__ W0, const float* __restrict__ b0,
    const float* __restrict__ W1, const float* __restrict__ b1,
    const float* __restrict__ bn_g, const float* __restrict__ bn_b,
    const float* __restrict__ bn_m, const float* __restrict__ bn_v,
    _Float16* __restrict__ seqh, _Float16* __restrict__ seql, int base)
{
  __shared__ float As[4096];
  __shared__ float Xs[1024];
  __shared__ float Hs[4096];
  __shared__ float Qs[4096];
  __shared__ float bnm_s[64], bns_s[64], bnb_s[64];

  const int t = threadIdx.x;
  const int lane = t & 63;
  const int w = t >> 6;
  const int m = base + blockIdx.x;

  {
    const float4* a4 = (const float4*)adj;
    float4* s4 = (float4*)As;
#pragma unroll
    for (int p = 0; p < 4; ++p) s4[t + 256 * p] = a4[t + 256 * p];
    ((float4*)Xs)[t] = ((const float4*)(x + (size_t)m * 1024))[t];
  }
  if (t < 64) {
    bns_s[t] = rsqrtf(bn_v[t] + EPS_BN) * bn_g[t];
    bnm_s[t] = bn_m[t];
    bnb_s[t] = bn_b[t];
  }
  float w0r[16];
#pragma unroll
  for (int f = 0; f < 16; ++f) w0r[f] = W0[f * 64 + lane];
  const float b0v = b0[lane], b1v = b1[lane];
  __syncthreads();

  float p[64];
#pragma unroll
  for (int v = 0; v < 64; ++v) {
    float acc = 0.f;
#pragma unroll
    for (int f = 0; f < 16; ++f) acc += Xs[v * 16 + f] * w0r[f];
    p[v] = acc;
  }
#pragma unroll
  for (int uu = 0; uu < 16; ++uu) {
    int u = w * 16 + uu;
    float acc = 0.f;
#pragma unroll
    for (int v = 0; v < 64; ++v) acc += As[u * 64 + v] * p[v];
    float h1 = fmaxf(acc + b0v, 0.f);
    h1 = (h1 - bnm_s[u]) * bns_s[u] + bnb_s[u];
    Hs[u * 64 + lane] = h1;
  }
  __syncthreads();
  float w1r[64];
#pragma unroll
  for (int f = 0; f < 64; ++f) w1r[f] = W1[f * 64 + lane];
#pragma unroll
  for (int vv = 0; vv < 16; ++vv) {
    int v = w * 16 + vv;
    float acc = 0.f;
#pragma unroll
    for (int f = 0; f < 64; ++f) acc += Hs[v * 64 + f] * w1r[f];
    Qs[v * 64 + lane] = acc;
  }
  __syncthreads();
  float q[64];
#pragma unroll
  for (int v = 0; v < 64; ++v) q[v] = Qs[v * 64 + lane];
  _Float16* oh = seqh + (size_t)blockIdx.x * 4096;
  _Float16* ol = seql + (size_t)blockIdx.x * 4096;
#pragma unroll
  for (int uu = 0; uu < 16; ++uu) {
    int u = w * 16 + uu;
    float acc = 0.f;
#pragma unroll
    for (int v = 0; v < 64; ++v) acc += As[u * 64 + v] * q[v];
    float val = fmaxf(acc + b1v, 0.f);
    _Float16 hv = (_Float16)val;
    oh[u * 64 + lane] = hv;
    ol[u * 64 + lane] = (_Float16)(val - (float)hv);
  }
}

// ----------------------------------------------- MFMA GEMM  C = A@B^T + bias
// 3-term hi/lo split, LDS-free. (unchanged from R6)
#define MFMA_VV(c, a, b) asm volatile("v_mfma_f32_16x16x32_f16 %0, %1, %2, %0" \
                                      : "+v"(c) : "v"(a), "v"(b))

__global__ __launch_bounds__(256, 2) void k_gemm_mfma(
    const _Float16* __restrict__ Ah, const _Float16* __restrict__ Al,
    const _Float16* __restrict__ Bh, const _Float16* __restrict__ Bl,
    const float* __restrict__ bias,
    float* __restrict__ C,
    int K, int mBlocks)
{
  const int bid = blockIdx.x;
  const int mb = bid % mBlocks;
  const int nb = bid / mBlocks;
  const int t = threadIdx.x;
  const int w = t >> 6, l = t & 63;
  const int m0 = mb * 128 + (w >> 1) * 64;
  const int n0 = nb * 128 + (w & 1) * 64;
  const int row = l & 15;
  const int kk = (l >> 4) * 8;

  const _Float16* ah = Ah + (size_t)(m0 + row) * K + kk;
  const _Float16* al = Al + (size_t)(m0 + row) * K + kk;
  const _Float16* bh = Bh + (size_t)(n0 + row) * K + kk;
  const _Float16* bl = Bl + (size_t)(n0 + row) * K + kk;

  f32x4 acc[4][4] = {};

  for (int kt = 0; kt < K; kt += 32) {
    u32x4v af_h[4], af_l[4], bf_h[4], bf_l[4];
#pragma unroll
    for (int i = 0; i < 4; ++i) {
      const size_t o = (size_t)(16 * i) * K + kt;
      af_h[i] = *(const u32x4v*)(ah + o);
      af_l[i] = *(const u32x4v*)(al + o);
      bf_h[i] = *(const u32x4v*)(bh + o);
      bf_l[i] = *(const u32x4v*)(bl + o);
    }
#pragma unroll
    for (int mi = 0; mi < 4; ++mi)
#pragma unroll
      for (int ni = 0; ni < 4; ++ni) {
        MFMA_VV(acc[mi][ni], af_h[mi], bf_h[ni]);
        MFMA_VV(acc[mi][ni], af_l[mi], bf_h[ni]);
        MFMA_VV(acc[mi][ni], af_h[mi], bf_l[ni]);
      }
  }

  asm volatile("s_nop 7\n\ts_nop 7");

  const int r4 = (l >> 4) * 4;
#pragma unroll
  for (int ni = 0; ni < 4; ++ni) {
    const float bv = bias[n0 + 16 * ni + row];
#pragma unroll
    for (int mi = 0; mi < 4; ++mi) {
      float* cp = C + (size_t)(m0 + 16 * mi + r4) * 768 + n0 + 16 * ni + row;
      cp[0]    = acc[mi][ni].x + bv;
      cp[768]  = acc[mi][ni].y + bv;
      cp[1536] = acc[mi][ni].z + bv;
      cp[2304] = acc[mi][ni].w + bv;
    }
  }
}

// ------------------------------------------------------------------ GRU layer
// R7: wave-local gates, one barrier/step, h2 double-buffered.
#define MFMA_A(c, a, b) asm volatile("v_mfma_f32_16x16x32_f16 %0, %1, %2, %0" \
                                     : "+v"(c) : "v"(a), "a"(b))
#define MFMA_V(c, a, b) asm volatile("v_mfma_f32_16x16x32_f16 %0, %1, %2, %0" \
                                     : "+v"(c) : "v"(a), "v"(b))

template <bool WF32, bool WF16>
__global__ __launch_bounds__(512, 2) void k_gru(
    const float* __restrict__ gi,        // [32*512][768]
    const uint4* __restrict__ wp,        // packed B-fragments (k_pack_frag)
    const float* __restrict__ bhh,       // [768]
    float* __restrict__ ys,              // [32*512][256] fp32   (if WF32)
    _Float16* __restrict__ ysh,          // [32*512][256] f16 hi (if WF16)
    _Float16* __restrict__ ysl)          // [32*512][256] f16 lo (if WF16)
{
  const int b = blockIdx.x;
  const int t = threadIdx.x;
  const int w = t >> 6;        // wave 0..7
  const int l = t & 63;

  __shared__ __align__(16) _Float16 h2[2][256];  // double-buffered f16 h
  __shared__ u32x4v blds[8][12][64];             // 96 KB: k-slices 6,7

  const u32x4v* wp4 = (const u32x4v*)wp;
  const int wbase = w * 6;

  // ---- B-fragments k-slices 0..5 -> named vars pinned to AGPR by "a" use
#define LBK(nt, ks) const u32x4v b##nt##_##ks = wp4[(((wbase + nt) * 8 + ks) << 6) + l];
#define LBNT(nt) LBK(nt,0) LBK(nt,1) LBK(nt,2) LBK(nt,3) LBK(nt,4) LBK(nt,5)
  LBNT(0) LBNT(1) LBNT(2) LBNT(3) LBNT(4) LBNT(5)
#undef LBNT
#undef LBK
  // ---- k-slices 6,7 -> LDS
#pragma unroll
  for (int nt = 0; nt < 6; ++nt) {
    blds[w][nt]    [l] = wp4[(((wbase + nt) * 8 + 6) << 6) + l];
    blds[w][6 + nt][l] = wp4[(((wbase + nt) * 8 + 7) << 6) + l];
  }

  // lane's output index: l<32 active, j = 16w + (l&15) + 128*(l>>4)
  const int half = (l >> 4) & 1;
  const int j = 16 * w + (l & 15) + 128 * half;
  const bool act = (l < 32);
  float br = 0.f, bz = 0.f, bn = 0.f;
  float hold = 0.f;
  if (act) { br = bhh[j]; bz = bhh[256 + j]; bn = bhh[512 + j]; }
  if (t < 256) { h2[0][t] = (_Float16)0.f; h2[1][t] = (_Float16)0.f; }
  __syncthreads();

  const float* gib = gi + (size_t)b * 512 * 768;
  const char* h2c = (const char*)h2;
  const int g16 = (l >> 4) * 16;
  int cur = 0;

#pragma unroll 1
  for (int step = 0; step < 512; ++step) {
    // prefetch gi for this step (latency hides under the dot)
    float ir = 0.f, iz = 0.f, inn = 0.f;
    if (act) {
      const float* g = gib + (size_t)step * 768;
      ir = g[j]; iz = g[256 + j]; inn = g[512 + j];
    }

    f32x4 c0 = {0.f,0.f,0.f,0.f}, c1 = c0, c2 = c0, c3 = c0, c4 = c0, c5 = c0;

#define DOT_KS(ks) { \
    const u32x4v a = *(const u32x4v*)(h2c + cur * 512 + (ks) * 64 + g16); \
    MFMA_A(c0, a, b0_##ks); MFMA_A(c1, a, b1_##ks); MFMA_A(c2, a, b2_##ks); \
    MFMA_A(c3, a, b3_##ks); MFMA_A(c4, a, b4_##ks); MFMA_A(c5, a, b5_##ks); }
    DOT_KS(0) DOT_KS(1) DOT_KS(2) DOT_KS(3) DOT_KS(4) DOT_KS(5)
#undef DOT_KS
    {
      const u32x4v a6 = *(const u32x4v*)(h2c + cur * 512 + 6 * 64 + g16);
      MFMA_V(c0, a6, blds[w][0][l]); MFMA_V(c1, a6, blds[w][1][l]);
      MFMA_V(c2, a6, blds[w][2][l]); MFMA_V(c3, a6, blds[w][3][l]);
      MFMA_V(c4, a6, blds[w][4][l]); MFMA_V(c5, a6, blds[w][5][l]);
      const u32x4v a7 = *(const u32x4v*)(h2c + cur * 512 + 7 * 64 + g16);
      MFMA_V(c0, a7, blds[w][6][l]);  MFMA_V(c1, a7, blds[w][7][l]);
      MFMA_V(c2, a7, blds[w][8][l]);  MFMA_V(c3, a7, blds[w][9][l]);
      MFMA_V(c4, a7, blds[w][10][l]); MFMA_V(c5, a7, blds[w][11][l]);
    }
    // MFMA-write -> VALU-read hazard guard
    asm volatile("s_nop 7\n\ts_nop 7");

    // wave-local gate math: half 0 uses c0/c2/c4, half 1 uses c1/c3/c5
    if (act) {
      const float cr = half ? c1.x : c0.x;
      const float cz = half ? c3.x : c2.x;
      const float cn = half ? c5.x : c4.x;
      const float r = __builtin_amdgcn_rcpf(1.f + __expf(-(ir + cr + br)));
      const float z = __builtin_amdgcn_rcpf(1.f + __expf(-(iz + cz + bz)));
      const float e2 = __expf(2.f * (inn + r * (cn + bn)));
      const float n = 1.f - 2.f * __builtin_amdgcn_rcpf(e2 + 1.f);
      hold = (1.f - z) * n + z * hold;
      h2[cur ^ 1][j] = (_Float16)hold;
      const size_t rowi = (size_t)b * 512 + step;
      if (WF32) ys[rowi * 256 + j] = hold;
      if (WF16) {
        const _Float16 hh = (_Float16)hold;
        ysh[rowi * 256 + j] = hh;
        ysl[rowi * 256 + j] = (_Float16)(hold - (float)hh);
      }
    }
    __syncthreads();
    cur ^= 1;
  }
}

// ------------------------------------------------------------------ FC head
__global__ __launch_bounds__(128) void k_head(
    const float* __restrict__ ys1,
    const float* __restrict__ fc1w, const float* __restrict__ fc1b,
    const float* __restrict__ fc2w, const float* __restrict__ fc2b,
    float* __restrict__ out)
{
  __shared__ float last[256];
  __shared__ float o1[128];
  const int b = blockIdx.x, t = threadIdx.x;
  const float* src = ys1 + (size_t)(b * 512 + 511) * 256;
  last[t] = src[t];
  last[128 + t] = src[128 + t];
  __syncthreads();
  float acc = fc1b[t];
#pragma unroll 8
  for (int k = 0; k < 256; ++k) acc += last[k] * fc1w[k * 128 + t];
  o1[t] = fmaxf(acc, 0.f);
  __syncthreads();
  if (t < 64) {
    float acc2 = fc2b[t];
#pragma unroll 8
    for (int i = 0; i < 128; ++i) acc2 += o1[i] * fc2w[i * 64 + t];
    out[b * 64 + t] = acc2;
  }
}

// ------------------------------------------------------------------ launcher
extern "C" void kernel_launch(void* const* d_in, const int* in_sizes, int n_in,
                              void* d_out, int out_size, void* d_ws, size_t ws_size,
                              hipStream_t stream)
{
  const float* x    = (const float*)d_in[0];
  const float* adj  = (const float*)d_in[1];
  const float* W0   = (const float*)d_in[2];
  const float* b0   = (const float*)d_in[3];
  const float* W1   = (const float*)d_in[4];
  const float* b1   = (const float*)d_in[5];
  const float* bng  = (const float*)d_in[6];
  const float* bnbb = (const float*)d_in[7];
  const float* bnm  = (const float*)d_in[8];
  const float* bnv  = (const float*)d_in[9];
  const float* Wih0 = (const float*)d_in[10];
  const float* Whh0 = (const float*)d_in[11];
  const float* bih0 = (const float*)d_in[12];
  const float* bhh0 = (const float*)d_in[13];
  const float* Wih1 = (const float*)d_in[14];
  const float* Whh1 = (const float*)d_in[15];
  const float* bih1 = (const float*)d_in[16];
  const float* bhh1 = (const float*)d_in[17];
  const float* fc1w = (const float*)d_in[18];
  const float* fc1b = (const float*)d_in[19];
  const float* fc2w = (const float*)d_in[20];
  const float* fc2b = (const float*)d_in[21];
  float* out = (float*)d_out;

  float* ws = (float*)d_ws;
  const size_t fixed = (size_t)16384 * 768 + (size_t)16384 * 256
                     + 2 * ((size_t)16384 * 128)
                     + 2 * 98304
                     + 2 * ((size_t)768 * 4096 / 2)
                     + 2 * ((size_t)768 * 256 / 2);
  int CHUNK = 16384;
  while (CHUNK > 128 && ((size_t)CHUNK * 4096 + fixed) * 4 > ws_size) CHUNK >>= 1;

  size_t off = 0;
  _Float16* seqh = (_Float16*)(ws + off); off += (size_t)CHUNK * 2048;
  _Float16* seql = (_Float16*)(ws + off); off += (size_t)CHUNK * 2048;
  float* gi      = ws + off; off += (size_t)16384 * 768;
  float* ys1     = ws + off; off += (size_t)16384 * 256;
  _Float16* ysh  = (_Float16*)(ws + off); off += (size_t)16384 * 128;
  _Float16* ysl  = (_Float16*)(ws + off); off += (size_t)16384 * 128;
  uint4* wp0     = (uint4*)(ws + off); off += 98304;
  uint4* wp1     = (uint4*)(ws + off); off += 98304;
  _Float16* bh0  = (_Float16*)(ws + off); off += (size_t)768 * 2048;
  _Float16* bl0  = (_Float16*)(ws + off); off += (size_t)768 * 2048;
  _Float16* bh1  = (_Float16*)(ws + off); off += (size_t)768 * 128;
  _Float16* bl1  = (_Float16*)(ws + off); off += (size_t)768 * 128;

  k_pack_frag<<<96, 256, 0, stream>>>(Whh0, wp0);
  k_pack_frag<<<96, 256, 0, stream>>>(Whh1, wp1);
  k_split16<<<(3145728 + 255) / 256, 256, 0, stream>>>(Wih0, bh0, bl0, 3145728);
  k_split16<<<(196608 + 255) / 256, 256, 0, stream>>>(Wih1, bh1, bl1, 196608);

  const int nChunks = 16384 / CHUNK;
  for (int ci = 0; ci < nChunks; ++ci) {
    const int base = ci * CHUNK;
    k_gcn<<<CHUNK, 256, 0, stream>>>(x, adj, W0, b0, W1, b1, bng, bnbb, bnm, bnv,
                                     seqh, seql, base);
    const int mB = CHUNK / 128;
    k_gemm_mfma<<<mB * 6, 256, 0, stream>>>(seqh, seql, bh0, bl0, bih0,
                                            gi + (size_t)base * 768, 4096, mB);
  }
  // GRU0: emits only f16 hi/lo (consumed by gi1 GEMM)
  k_gru<false, true><<<32, 512, 0, stream>>>(gi, wp0, bhh0, nullptr, ysh, ysl);
  k_gemm_mfma<<<128 * 6, 256, 0, stream>>>(ysh, ysl, bh1, bl1, bih1, gi, 256, 128);
  // GRU1: emits only fp32 (consumed by head)
  k_gru<true, false><<<32, 512, 0, stream>>>(gi, wp1, bhh1, ys1, nullptr, nullptr);
  k_head<<<32, 128, 0, stream>>>(ys1, fc1w, fc1b, fc2w, fc2b, out);
}